// Round 9
// baseline (118.062 us; speedup 1.0000x reference)
//
#include <hip/hip_runtime.h>

namespace {
constexpr int CIN = 64, COUT = 64, SS = 1024, KK = 3;
constexpr int STILE = 64;   // s per block: 64 lanes -> 768-B contiguous weight runs
constexpr int PF    = 4;    // weight prefetch depth (c-iterations)
}

struct F3 { float x, y, z; };   // one (o,c,s) weight chunk -> global_load_dwordx3

// R9: weight-stream CONTIGUITY. Theory: R4-R8 all hit ~1.6 TB/s because the
// s-tile-4 slab shape makes every weight access a 48-B stripe at 12-KB stride
// (DRAM row thrash). Here lane=s: each wave-instruction reads 768 B contiguous
// of w[o][c][s0:s0+64][k]. Block = (o-quad, s-tile-64), thread = (s, 4 o, 4 b),
// ALL 64 c serial per thread -> no reduction, no LDS, no barriers, no drains.
// Ring buffers with compile-time indices only (R3: runtime index -> scratch).
__global__ __launch_bounds__(256, 1)
void locon1d(const float* __restrict__ in, const float* __restrict__ wt,
             const float* __restrict__ bias, float* __restrict__ out) {
  const int tid  = threadIdx.x;
  const int lane = tid & 63;
  const int bq   = tid >> 6;          // wave id = b-quad (4 b's)
  const int bid  = blockIdx.x;
  const int st   = bid & 15;          // same-st o-quads: bid%8 == st%8 -> same XCD (x L2 reuse)
  const int oq   = bid >> 4;
  const int s0   = st * STILE;
  const int s    = s0 + lane;
  const int o0   = oq * 4;

  const float* wbase = wt + (size_t)o0 * CIN * SS * KK + (size_t)s * KK;

  float acc[4][4];                    // [o][b]
  #pragma unroll
  for (int oo = 0; oo < 4; ++oo)
    #pragma unroll
    for (int j = 0; j < 4; ++j) acc[oo][j] = 0.f;

  F3    wv[PF][4];                    // weight ring: PF c-steps x 4 o
  float xv[2][4][3];                  // x ring: 2 c-steps x 4 b x 3 taps

  auto loadW = [&](int c, int slot) {             // slot is always a literal
    #pragma unroll
    for (int oo = 0; oo < 4; ++oo)
      wv[slot][oo] =
          *reinterpret_cast<const F3*>(wbase + ((size_t)oo * CIN + c) * SS * KK);
  };
  auto loadX = [&](int c, int buf) {              // buf is always a literal
    #pragma unroll
    for (int j = 0; j < 4; ++j) {
      const float* xp = in + ((size_t)(4 * bq + j) * CIN + c) * SS;
      #pragma unroll
      for (int t = 0; t < 3; ++t) {
        const int sg = s + t - 1;
        float v = 0.f;
        if ((unsigned)sg < (unsigned)SS) v = xp[sg];
        xv[buf][j][t] = v;
      }
    }
  };

  // prologue: fill rings
  #pragma unroll
  for (int c = 0; c < PF; ++c) loadW(c, c);
  loadX(0, 0);

  for (int cc = 0; cc < CIN / PF; ++cc) {         // runtime outer: I-cache friendly
    #pragma unroll
    for (int u = 0; u < PF; ++u) {                // compile-time ring indices
      const int c = cc * PF + u;
      if (c + 1 < CIN) loadX(c + 1, (u + 1) & 1); // prefetch next x
      #pragma unroll
      for (int oo = 0; oo < 4; ++oo) {
        const F3 w3 = wv[u][oo];
        #pragma unroll
        for (int j = 0; j < 4; ++j) {
          acc[oo][j] += w3.x * xv[u & 1][j][0];
          acc[oo][j] += w3.y * xv[u & 1][j][1];
          acc[oo][j] += w3.z * xv[u & 1][j][2];
        }
      }
      if (cc + 1 < CIN / PF) loadW(c + PF, u);    // refill ring slot
    }
  }

  // epilogue: direct coalesced stores (lanes = consecutive s), bias fused
  #pragma unroll
  for (int oo = 0; oo < 4; ++oo) {
    const int o = o0 + oo;
    const float bz = bias[(size_t)o * SS + s];
    #pragma unroll
    for (int j = 0; j < 4; ++j)
      out[((size_t)(4 * bq + j) * COUT + o) * SS + s] = acc[oo][j] + bz;
  }
}

extern "C" void kernel_launch(void* const* d_in, const int* in_sizes, int n_in,
                              void* d_out, int out_size, void* d_ws, size_t ws_size,
                              hipStream_t stream) {
  const float* in = (const float*)d_in[0];
  const float* wt = (const float*)d_in[1];
  const float* bs = (const float*)d_in[2];
  float* out = (float*)d_out;
  // 16 o-quads x 16 s-tiles = 256 blocks x 256 thr -> 1 block/CU, no barriers
  hipLaunchKernelGGL(locon1d, dim3(256), dim3(256), 0, stream, in, wt, bs, out);
}